// Round 3
// baseline (107.935 us; speedup 1.0000x reference)
//
#include <hip/hip_runtime.h>

#define BATCH 512
#define DIN 512
#define NCLS 16
#define NNODES 100000
#define CBLK 256
#define NODE_BLOCKS ((NNODES + CBLK - 1) / CBLK)   // 391

// ---- workspace layout (bytes) ----
// val:   [0, 1601536)            391 x 512 u64 packed per-block per-sample max
// probs: [1601536, 1634304)      512 x 16 f32
// emb:   [1634304, 1638400)      512 x 2 f32
// pcls:  [1638400, 1640448)      512 x i32 predicted class
// mse:   [1640448, 1642496)      512 x f32 per-sample mse
// done:  [1642496, 1642500)      1 x u32
#define WS_VAL   0
#define WS_PROBS 1601536
#define WS_EMB   1634304
#define WS_PCLS  1638400
#define WS_MSE   1640448
#define WS_DONE  1642496

__device__ __forceinline__ unsigned ford(float f) {
    unsigned bits = __float_as_uint(f);
    return (bits & 0x80000000u) ? ~bits : (bits | 0x80000000u);
}

// 65 blocks x 512 threads.
// Blocks 0..63: emb = train_data @ W + b, one sample per wave (8 waves/block).
// Block 64:     per-sample softmax + argmax class, init done.
__global__ __launch_bounds__(512) void prep_kernel(
    const float* __restrict__ logits,
    const float* __restrict__ train_data,
    const float* __restrict__ W,
    const float* __restrict__ bvec,
    float* __restrict__ probs,
    float* __restrict__ emb,
    int* __restrict__ pcls,
    unsigned int* __restrict__ done) {
    if (blockIdx.x < 64) {
        const int wave = threadIdx.x >> 6;
        const int lane = threadIdx.x & 63;
        const int s = blockIdx.x * 8 + wave;
        const float* td = train_data + s * DIN;
        const float2* W2 = (const float2*)W;
        float a0 = 0.f, a1 = 0.f;
        for (int k = lane; k < DIN; k += 64) {
            float t = td[k];
            float2 w = W2[k];
            a0 += t * w.x;
            a1 += t * w.y;
        }
        for (int off = 32; off; off >>= 1) {
            a0 += __shfl_down(a0, off);
            a1 += __shfl_down(a1, off);
        }
        if (lane == 0) {
            emb[2 * s]     = a0 + bvec[0];
            emb[2 * s + 1] = a1 + bvec[1];
        }
    } else {
        const int s = threadIdx.x;
        const float4* lg = (const float4*)(logits + s * NCLS);
        float4 x0 = lg[0], x1 = lg[1], x2 = lg[2], x3 = lg[3];
        float v[NCLS] = {x0.x, x0.y, x0.z, x0.w, x1.x, x1.y, x1.z, x1.w,
                         x2.x, x2.y, x2.z, x2.w, x3.x, x3.y, x3.z, x3.w};
        float m = v[0];
        int pred = 0;
        #pragma unroll
        for (int j = 1; j < NCLS; ++j)
            if (v[j] > m) { m = v[j]; pred = j; }
        float sum = 0.f;
        #pragma unroll
        for (int j = 0; j < NCLS; ++j) { v[j] = expf(v[j] - m); sum += v[j]; }
        float inv = 1.0f / sum;
        float4* p4 = (float4*)(probs + s * NCLS);
        p4[0] = make_float4(v[0] * inv, v[1] * inv, v[2] * inv, v[3] * inv);
        p4[1] = make_float4(v[4] * inv, v[5] * inv, v[6] * inv, v[7] * inv);
        p4[2] = make_float4(v[8] * inv, v[9] * inv, v[10] * inv, v[11] * inv);
        p4[3] = make_float4(v[12] * inv, v[13] * inv, v[14] * inv, v[15] * inv);
        pcls[s] = pred;
        if (s == 0) *done = 0u;
    }
}

// 391 blocks x 256 threads. Class-major: stage tile's nodes in LDS, each
// thread owns 2 samples (probs + running max in registers), scans only the
// same-class nodes of the tile. Zero atomics on the hot path; coalesced
// per-(block,sample) u64 result stores.
__global__ __launch_bounds__(256) void nodes_kernel(
    const float* __restrict__ all_nodes,
    const float* __restrict__ probs,
    const int* __restrict__ pcls,
    unsigned long long* __restrict__ val) {
    __shared__ float4 snode[4 * CBLK];            // [j][n], 16 KB
    __shared__ float sinv[CBLK];                  // 1 KB
    __shared__ unsigned short clist[NCLS * CBLK]; // 8 KB
    __shared__ int scnt[NCLS];

    const int t = threadIdx.x;
    if (t < NCLS) scnt[t] = 0;
    __syncthreads();

    const int nid = blockIdx.x * CBLK + t;
    if (nid < NNODES) {
        const float4* nv = (const float4*)(all_nodes + nid * NCLS);
        float4 v0 = nv[0], v1 = nv[1], v2 = nv[2], v3 = nv[3];
        float vals[NCLS] = {v0.x, v0.y, v0.z, v0.w, v1.x, v1.y, v1.z, v1.w,
                            v2.x, v2.y, v2.z, v2.w, v3.x, v3.y, v3.z, v3.w};
        int cls = 0;
        float m = vals[0];
        float nrm2 = 0.f;
        #pragma unroll
        for (int j = 0; j < NCLS; ++j) {
            if (j > 0 && vals[j] > m) { m = vals[j]; cls = j; }
            nrm2 += vals[j] * vals[j];
        }
        snode[t]            = v0;
        snode[CBLK + t]     = v1;
        snode[2 * CBLK + t] = v2;
        snode[3 * CBLK + t] = v3;
        sinv[t] = 1.0f / sqrtf(nrm2);
        int pos = atomicAdd(&scnt[cls], 1);
        clist[cls * CBLK + pos] = (unsigned short)t;
    }
    __syncthreads();

    const int base = blockIdx.x * CBLK;
    #pragma unroll
    for (int h = 0; h < 2; ++h) {
        const int s = t + h * CBLK;
        const float4* p4 = (const float4*)(probs + s * NCLS);
        float4 a0 = p4[0], a1 = p4[1], a2 = p4[2], a3 = p4[3];
        const int c = pcls[s];
        const int cnt = scnt[c];
        const unsigned short* lst = &clist[c * CBLK];
        unsigned long long best = 0ull;
        for (int i = 0; i < cnt; ++i) {
            const int n = lst[i];
            float4 v0 = snode[n];
            float4 v1 = snode[CBLK + n];
            float4 v2 = snode[2 * CBLK + n];
            float4 v3 = snode[3 * CBLK + n];
            float dot = a0.x * v0.x + a0.y * v0.y + a0.z * v0.z + a0.w * v0.w
                      + a1.x * v1.x + a1.y * v1.y + a1.z * v1.z + a1.w * v1.w
                      + a2.x * v2.x + a2.y * v2.y + a2.z * v2.z + a2.w * v2.w
                      + a3.x * v3.x + a3.y * v3.y + a3.z * v3.z + a3.w * v3.w;
            float sim = dot * sinv[n];
            unsigned long long packed =
                ((unsigned long long)ford(sim) << 32)
                | (unsigned long long)(0xFFFFFFFFu - (unsigned)(base + n));
            best = (packed > best) ? packed : best;
        }
        val[blockIdx.x * BATCH + s] = best;
    }
}

// 512 blocks x 64 threads: block s = per-sample max over 391 block results,
// then per-sample MSE; last-done block reduces the mean -> out[0].
__global__ __launch_bounds__(64) void merge_kernel(
    const unsigned long long* __restrict__ val,
    const float* __restrict__ emb,
    const float* __restrict__ all_nodes_2d,
    float* __restrict__ mse,
    unsigned int* __restrict__ done,
    float* __restrict__ out) {
    const int s = blockIdx.x;
    const int k = threadIdx.x;

    unsigned long long m = 0ull;
    for (int b = k; b < NODE_BLOCKS; b += 64) {
        unsigned long long v = val[b * BATCH + s];
        m = (v > m) ? v : m;
    }
    for (int off = 32; off; off >>= 1) {
        unsigned long long o = __shfl_down(m, off);
        m = (o > m) ? o : m;
    }
    if (k == 0) {
        int idx = (m == 0ull) ? 0
                              : (int)(0xFFFFFFFFu - (unsigned)(m & 0xFFFFFFFFull));
        float2 tg = ((const float2*)all_nodes_2d)[idx];
        float2 e = ((const float2*)emb)[s];
        float d0 = e.x - tg.x;
        float d1 = e.y - tg.y;
        mse[s] = 0.5f * (d0 * d0 + d1 * d1);
    }
    __threadfence();
    unsigned ticket = 0u;
    if (k == 0) ticket = atomicAdd(done, 1u);
    ticket = __shfl(ticket, 0);
    if (ticket == (unsigned)(gridDim.x - 1)) {
        __threadfence();
        float ssum = 0.f;
        for (int i = k; i < BATCH; i += 64) ssum += mse[i];
        for (int off = 32; off; off >>= 1) ssum += __shfl_down(ssum, off);
        if (k == 0) out[0] = ssum / (float)BATCH;
    }
}

extern "C" void kernel_launch(void* const* d_in, const int* in_sizes, int n_in,
                              void* d_out, int out_size, void* d_ws, size_t ws_size,
                              hipStream_t stream) {
    const float* logits       = (const float*)d_in[0];
    const float* train_data   = (const float*)d_in[1];
    const float* all_nodes    = (const float*)d_in[2];
    const float* all_nodes_2d = (const float*)d_in[3];
    const float* W            = (const float*)d_in[4];
    const float* bvec         = (const float*)d_in[5];
    float* out = (float*)d_out;

    char* ws = (char*)d_ws;
    unsigned long long* val = (unsigned long long*)(ws + WS_VAL);
    float* probs            = (float*)(ws + WS_PROBS);
    float* emb              = (float*)(ws + WS_EMB);
    int* pcls               = (int*)(ws + WS_PCLS);
    float* mse              = (float*)(ws + WS_MSE);
    unsigned int* done      = (unsigned int*)(ws + WS_DONE);

    prep_kernel<<<65, 512, 0, stream>>>(logits, train_data, W, bvec,
                                        probs, emb, pcls, done);

    nodes_kernel<<<NODE_BLOCKS, CBLK, 0, stream>>>(all_nodes, probs, pcls, val);

    merge_kernel<<<BATCH, 64, 0, stream>>>(val, emb, all_nodes_2d,
                                           mse, done, out);
}

// Round 5
// 106.746 us; speedup vs baseline: 1.0111x; 1.0111x over previous
//
#include <hip/hip_runtime.h>

#define BATCH 512
#define DIN 512
#define NCLS 16
#define NNODES 100000
#define CBLK 256
#define NODE_BLOCKS ((NNODES + CBLK - 1) / CBLK)   // 391

// ---- workspace layout (bytes) ----
// val:        [0, 1601536)           391 x 512 u64, per-(block,slot) packed max
// probs:      [1601536, 1634304)     512 x 16 f32
// sorted_ids: [1634304, 1636352)     512 x i32 (sample id per class-sorted slot)
// slot_cls:   [1636352, 1638400)     512 x i32 (class per slot)
// mse:        [1638400, 1640448)     512 x f32
// done:       [1640448, 1640452)     u32
#define WS_VAL   0
#define WS_PROBS 1601536
#define WS_SORT  1634304
#define WS_SCLS  1636352
#define WS_MSE   1638400
#define WS_DONE  1640448

__device__ __forceinline__ unsigned ford(float f) {
    unsigned bits = __float_as_uint(f);
    return (bits & 0x80000000u) ? ~bits : (bits | 0x80000000u);
}

// 1 block x 512 threads: softmax + argmax per sample, counting-sort by class.
__global__ __launch_bounds__(512) void prep_kernel(
    const float* __restrict__ logits,
    float* __restrict__ probs,
    int* __restrict__ sorted_ids,
    int* __restrict__ slot_cls,
    unsigned int* __restrict__ done) {
    __shared__ int scnt[NCLS];
    __shared__ int soff[NCLS + 1];
    const int s = threadIdx.x;
    if (s < NCLS) scnt[s] = 0;
    __syncthreads();

    const float4* lg = (const float4*)(logits + s * NCLS);
    float4 x0 = lg[0], x1 = lg[1], x2 = lg[2], x3 = lg[3];
    float v[NCLS] = {x0.x, x0.y, x0.z, x0.w, x1.x, x1.y, x1.z, x1.w,
                     x2.x, x2.y, x2.z, x2.w, x3.x, x3.y, x3.z, x3.w};
    float m = v[0];
    int pred = 0;
    #pragma unroll
    for (int j = 1; j < NCLS; ++j)
        if (v[j] > m) { m = v[j]; pred = j; }
    float sum = 0.f;
    #pragma unroll
    for (int j = 0; j < NCLS; ++j) { v[j] = expf(v[j] - m); sum += v[j]; }
    float inv = 1.0f / sum;
    float4* p4 = (float4*)(probs + s * NCLS);
    p4[0] = make_float4(v[0] * inv, v[1] * inv, v[2] * inv, v[3] * inv);
    p4[1] = make_float4(v[4] * inv, v[5] * inv, v[6] * inv, v[7] * inv);
    p4[2] = make_float4(v[8] * inv, v[9] * inv, v[10] * inv, v[11] * inv);
    p4[3] = make_float4(v[12] * inv, v[13] * inv, v[14] * inv, v[15] * inv);

    int pos = atomicAdd(&scnt[pred], 1);
    __syncthreads();
    if (s == 0) {
        int acc = 0;
        for (int c = 0; c < NCLS; ++c) { soff[c] = acc; acc += scnt[c]; }
        soff[NCLS] = acc;
        *done = 0u;
    }
    __syncthreads();
    const int slot = soff[pred] + pos;
    sorted_ids[slot] = s;
    slot_cls[slot] = pred;
}

// 391 blocks x 256 threads. Stage 256 nodes in LDS with per-class lists; each
// thread scans 2 class-sorted slots. Same-class lanes read identical LDS
// addresses (broadcast, conflict-free) and share trip counts (low divergence).
__global__ __launch_bounds__(256) void nodes_kernel(
    const float* __restrict__ all_nodes,
    const float* __restrict__ probs,
    const int* __restrict__ sorted_ids,
    const int* __restrict__ slot_cls,
    unsigned long long* __restrict__ val) {
    __shared__ float4 snode[4 * CBLK];            // [j][n], 16 KB
    __shared__ float sinv[CBLK];                  // 1 KB
    __shared__ unsigned short clist[NCLS * CBLK]; // 8 KB
    __shared__ int scnt[NCLS];

    const int t = threadIdx.x;
    if (t < NCLS) scnt[t] = 0;
    __syncthreads();

    const int nid = blockIdx.x * CBLK + t;
    if (nid < NNODES) {
        const float4* nv = (const float4*)(all_nodes + nid * NCLS);
        float4 v0 = nv[0], v1 = nv[1], v2 = nv[2], v3 = nv[3];
        float vals[NCLS] = {v0.x, v0.y, v0.z, v0.w, v1.x, v1.y, v1.z, v1.w,
                            v2.x, v2.y, v2.z, v2.w, v3.x, v3.y, v3.z, v3.w};
        int cls = 0;
        float m = vals[0];
        float nrm2 = 0.f;
        #pragma unroll
        for (int j = 0; j < NCLS; ++j) {
            if (j > 0 && vals[j] > m) { m = vals[j]; cls = j; }
            nrm2 += vals[j] * vals[j];
        }
        snode[t]            = v0;
        snode[CBLK + t]     = v1;
        snode[2 * CBLK + t] = v2;
        snode[3 * CBLK + t] = v3;
        sinv[t] = 1.0f / sqrtf(nrm2);
        int pos = atomicAdd(&scnt[cls], 1);
        clist[cls * CBLK + pos] = (unsigned short)t;
    }
    __syncthreads();

    const int base = blockIdx.x * CBLK;
    #pragma unroll
    for (int h = 0; h < 2; ++h) {
        const int slot = t + h * CBLK;
        const int s = sorted_ids[slot];
        const int c = slot_cls[slot];
        const float4* p4 = (const float4*)(probs + s * NCLS);
        float4 a0 = p4[0], a1 = p4[1], a2 = p4[2], a3 = p4[3];
        const int cnt = scnt[c];
        const unsigned short* lst = &clist[c * CBLK];
        unsigned long long best = 0ull;
        for (int i = 0; i < cnt; ++i) {
            const int n = lst[i];
            float4 v0 = snode[n];
            float4 v1 = snode[CBLK + n];
            float4 v2 = snode[2 * CBLK + n];
            float4 v3 = snode[3 * CBLK + n];
            float dot = a0.x * v0.x + a0.y * v0.y + a0.z * v0.z + a0.w * v0.w
                      + a1.x * v1.x + a1.y * v1.y + a1.z * v1.z + a1.w * v1.w
                      + a2.x * v2.x + a2.y * v2.y + a2.z * v2.z + a2.w * v2.w
                      + a3.x * v3.x + a3.y * v3.y + a3.z * v3.z + a3.w * v3.w;
            float sim = dot * sinv[n];
            unsigned long long packed =
                ((unsigned long long)ford(sim) << 32)
                | (unsigned long long)(0xFFFFFFFFu - (unsigned)(base + n));
            best = (packed > best) ? packed : best;
        }
        val[blockIdx.x * BATCH + slot] = best;   // coalesced, slot-indexed
    }
}

// 512 blocks x 64 threads: block j owns sorted slot j -> sample s.
// Does emb GEMV for s, per-slot max over 391 block results, MSE;
// last-done block reduces the mean -> out[0].
__global__ __launch_bounds__(64) void merge_kernel(
    const float* __restrict__ train_data,
    const float* __restrict__ W,
    const float* __restrict__ bvec,
    const int* __restrict__ sorted_ids,
    const unsigned long long* __restrict__ val,
    const float* __restrict__ all_nodes_2d,
    float* __restrict__ mse,
    unsigned int* __restrict__ done,
    float* __restrict__ out) {
    const int j = blockIdx.x;
    const int k = threadIdx.x;
    const int s = sorted_ids[j];

    // emb[s] = train_data[s] @ W + b
    float a0 = 0.f, a1 = 0.f;
    const float* td = train_data + s * DIN;
    const float2* W2 = (const float2*)W;
    for (int kk = k; kk < DIN; kk += 64) {
        float t = td[kk];
        float2 w = W2[kk];
        a0 += t * w.x;
        a1 += t * w.y;
    }

    unsigned long long m = 0ull;
    for (int b = k; b < NODE_BLOCKS; b += 64) {
        unsigned long long v = val[b * BATCH + j];
        m = (v > m) ? v : m;
    }

    for (int off = 32; off; off >>= 1) {
        a0 += __shfl_down(a0, off);
        a1 += __shfl_down(a1, off);
        unsigned long long o = __shfl_down(m, off);
        m = (o > m) ? o : m;
    }

    if (k == 0) {
        float e0 = a0 + bvec[0];
        float e1 = a1 + bvec[1];
        int idx = (m == 0ull) ? 0
                              : (int)(0xFFFFFFFFu - (unsigned)(m & 0xFFFFFFFFull));
        float2 tg = ((const float2*)all_nodes_2d)[idx];
        float d0 = e0 - tg.x;
        float d1 = e1 - tg.y;
        mse[s] = 0.5f * (d0 * d0 + d1 * d1);
    }
    __threadfence();
    unsigned ticket = 0u;
    if (k == 0) ticket = atomicAdd(done, 1u);
    ticket = __shfl(ticket, 0);
    if (ticket == (unsigned)(gridDim.x - 1)) {
        __threadfence();
        float ssum = 0.f;
        for (int i = k; i < BATCH; i += 64) ssum += mse[i];
        for (int off = 32; off; off >>= 1) ssum += __shfl_down(ssum, off);
        if (k == 0) out[0] = ssum / (float)BATCH;
    }
}

extern "C" void kernel_launch(void* const* d_in, const int* in_sizes, int n_in,
                              void* d_out, int out_size, void* d_ws, size_t ws_size,
                              hipStream_t stream) {
    const float* logits       = (const float*)d_in[0];
    const float* train_data   = (const float*)d_in[1];
    const float* all_nodes    = (const float*)d_in[2];
    const float* all_nodes_2d = (const float*)d_in[3];
    const float* W            = (const float*)d_in[4];
    const float* bvec         = (const float*)d_in[5];
    float* out = (float*)d_out;

    char* ws = (char*)d_ws;
    unsigned long long* val = (unsigned long long*)(ws + WS_VAL);
    float* probs            = (float*)(ws + WS_PROBS);
    int* sorted_ids         = (int*)(ws + WS_SORT);
    int* slot_cls           = (int*)(ws + WS_SCLS);
    float* mse              = (float*)(ws + WS_MSE);
    unsigned int* done      = (unsigned int*)(ws + WS_DONE);

    prep_kernel<<<1, BATCH, 0, stream>>>(logits, probs, sorted_ids,
                                         slot_cls, done);

    nodes_kernel<<<NODE_BLOCKS, CBLK, 0, stream>>>(all_nodes, probs,
                                                   sorted_ids, slot_cls, val);

    merge_kernel<<<BATCH, 64, 0, stream>>>(train_data, W, bvec, sorted_ids,
                                           val, all_nodes_2d, mse, done, out);
}